// Round 5
// baseline (359.096 us; speedup 1.0000x reference)
//
#include <hip/hip_runtime.h>
#include <math.h>

// ChannelDropout: out[b,c,t] = sig[b,c,t] * kept[b,c] / (1e-8 + proba[b,c])
//   kept[b,c]  = ||pos[b,c] - center|| > 0.2
//   proba[b,c] = mean_i( ||pos[b,c] - mc[i]|| > 0.2 ), i in [0,100)
//
// Grid-stride persistent-block version of the round-4 kernel:
//  - 2048 blocks (8 blocks/CU x 256 CU, all co-resident), each grid-strides
//    over ~8.5 rows. Workgroup dispatch count drops 17472 -> 2048.
//  - pos for row k+stride is prefetched DURING row k's MC loop + stores, so
//    the kept-branch at each iteration start is register-resolved and the
//    sig staged loads issue immediately (round 4 serialized pos-load ->
//    branch -> sig-load at every block start).
//  - Keeps all prior verified wins: kept==0 rows store zeros and skip the
//    12 KB sig read + MC loop (~25 MB saved); 4-deep float4 staging (stays
//    under the 64-VGPR occupancy cliff -- round-3 lesson); wave-redundant
//    scale with __shfl_xor butterfly (no LDS, no barrier); nontemporal
//    loads/stores (touch-once streams, 395 MB >> L3).
//  - NOTE numerics: keep sqrtf(d2) > 0.2f (not d2 > 0.04f) so borderline
//    comparisons round identically to the JAX reference.

typedef float v4f __attribute__((ext_vector_type(4)));

__global__ __launch_bounds__(256) void channel_dropout_kernel(
    const float* __restrict__ sig,
    const float* __restrict__ pos,
    const float* __restrict__ center,
    const float* __restrict__ mc,
    float* __restrict__ out,
    int rows, int T, int NMC)
{
    const int t      = threadIdx.x;
    const int lane   = t & 63;
    const int stride = gridDim.x;
    const int n4     = T >> 2;             // 750 for T=3000

    const float cx = center[0];
    const float cy = center[1];

    int row = blockIdx.x;
    if (row >= rows) return;

    // first row's position (only block-start where this latency is exposed)
    float px = pos[2 * (size_t)row + 0];
    float py = pos[2 * (size_t)row + 1];

    while (row < rows) {
        const int nrow = row + stride;
        const size_t base = (size_t)row * (size_t)T;
        const v4f* __restrict__ in4  = (const v4f*)(sig + base);
        v4f* __restrict__       out4 = (v4f*)(out + base);

        // kept-check: px,py already in registers (prefetched last iter)
        const float ddx = px - cx;
        const float ddy = py - cy;
        const bool kept = sqrtf(ddx * ddx + ddy * ddy) > 0.2f;

        float scale = 0.0f;
        v4f v[4];
        if (kept) {
            // issue the streaming loads first
            #pragma unroll
            for (int u = 0; u < 4; ++u) {
                const int i = t + u * 256;
                if (i < n4) v[u] = __builtin_nontemporal_load(in4 + i);
            }
        }

        // prefetch next row's position (hidden under MC loop + stores)
        float npx = px, npy = py;
        if (nrow < rows) {
            npx = pos[2 * (size_t)nrow + 0];
            npy = pos[2 * (size_t)nrow + 1];
        }

        if (kept) {
            // per-wave redundant MC count (overlaps in-flight sig loads)
            float cnt = 0.0f;
            for (int i = lane; i < NMC; i += 64) {
                const float dx = px - mc[2 * i + 0];
                const float dy = py - mc[2 * i + 1];
                cnt += (sqrtf(dx * dx + dy * dy) > 0.2f) ? 1.0f : 0.0f;
            }
            #pragma unroll
            for (int off = 32; off > 0; off >>= 1)
                cnt += __shfl_xor(cnt, off, 64);
            scale = 1.0f / (1e-8f + cnt / (float)NMC);  // kept == 1

            #pragma unroll
            for (int u = 0; u < 4; ++u) {
                const int i = t + u * 256;
                if (i < n4) {
                    v4f r = v[u];
                    r *= scale;
                    __builtin_nontemporal_store(r, out4 + i);
                }
            }
            // generic remainder for n4 > 1024 (not hit at T=3000)
            for (int i = t + 1024; i < n4; i += 256) {
                v4f r = __builtin_nontemporal_load(in4 + i);
                r *= scale;
                __builtin_nontemporal_store(r, out4 + i);
            }
            for (int i = (n4 << 2) + t; i < T; i += 256) {
                out[base + i] = sig[base + i] * scale;
            }
        } else {
            // dropped channel: exact zeros, no sig read, no MC loop
            const v4f z = {0.0f, 0.0f, 0.0f, 0.0f};
            #pragma unroll
            for (int u = 0; u < 4; ++u) {
                const int i = t + u * 256;
                if (i < n4) __builtin_nontemporal_store(z, out4 + i);
            }
            for (int i = t + 1024; i < n4; i += 256)
                __builtin_nontemporal_store(z, out4 + i);
            for (int i = (n4 << 2) + t; i < T; i += 256)
                out[base + i] = 0.0f;
        }

        px = npx; py = npy;
        row = nrow;
    }
}

extern "C" void kernel_launch(void* const* d_in, const int* in_sizes, int n_in,
                              void* d_out, int out_size, void* d_ws, size_t ws_size,
                              hipStream_t stream) {
    const float* sig    = (const float*)d_in[0];  // (B, C, T) f32
    const float* pos    = (const float*)d_in[1];  // (B, C, 2) f32
    const float* center = (const float*)d_in[2];  // (2,)      f32
    const float* mc     = (const float*)d_in[3];  // (N, 2)    f32
    float* out          = (float*)d_out;          // (B, C, T) f32

    const int rows = in_sizes[1] / 2;             // B*C = 17472
    const int T    = in_sizes[0] / rows;          // 3000
    const int NMC  = in_sizes[3] / 2;             // 100

    const int blocks = rows < 2048 ? rows : 2048; // 8 blocks/CU, co-resident
    channel_dropout_kernel<<<blocks, 256, 0, stream>>>(
        sig, pos, center, mc, out, rows, T, NMC);
}

// Round 6
// 339.381 us; speedup vs baseline: 1.0581x; 1.0581x over previous
//
#include <hip/hip_runtime.h>
#include <math.h>

// ChannelDropout: out[b,c,t] = sig[b,c,t] * kept[b,c] / (1e-8 + proba[b,c])
//   kept[b,c]  = ||pos[b,c] - center|| > 0.2
//   proba[b,c] = mean_i( ||pos[b,c] - mc[i]|| > 0.2 ), i in [0,100)
//
// FINAL (round-4 structure, best measured 337.1 us): block-per-row, 4-deep
// float4 staging, wave-redundant scale, no LDS/no barrier, nontemporal,
// kept-skip.
//  - kept depends only on pos/center. If kept==0 the output row is exactly
//    0.0 regardless of sig -> store zeros, SKIP the 12 KB sig read and the
//    100-center MC loop (~12% of rows, ~25 MB less read traffic).
//  - 4-deep staging stays under the 64-VGPR occupancy cliff (round-3
//    lesson: 6-deep halved occupancy, -10%).
//  - Fused single dispatch (round-2 lesson: a split pays a dispatch
//    boundary that exceeds the prologue savings).
//  - Block-per-row with HW dispatch, NOT grid-stride persistent blocks
//    (round-5 lesson: static row assignment loses the dispatcher's load
//    balancing across kept/dropped rows, -15 us).
//  - NOTE numerics: keep sqrtf(d2) > 0.2f (not d2 > 0.04f) so borderline
//    comparisons round identically to the JAX reference.

typedef float v4f __attribute__((ext_vector_type(4)));

__global__ __launch_bounds__(256) void channel_dropout_kernel(
    const float* __restrict__ sig,
    const float* __restrict__ pos,
    const float* __restrict__ center,
    const float* __restrict__ mc,
    float* __restrict__ out,
    int T, int NMC)
{
    const int row  = blockIdx.x;           // b*C + c
    const int t    = threadIdx.x;
    const int lane = t & 63;

    const size_t base = (size_t)row * (size_t)T;
    const int n4 = T >> 2;                 // 750 float4 per row (T=3000)
    const v4f* __restrict__ in4  = (const v4f*)(sig + base);
    v4f* __restrict__       out4 = (v4f*)(out + base);

    // ---- kept check first (pos/center are L2-hot; block-uniform) ---------
    const float px  = pos[2 * (size_t)row + 0];
    const float py  = pos[2 * (size_t)row + 1];
    const float ddx = px - center[0];
    const float ddy = py - center[1];
    const bool kept = sqrtf(ddx * ddx + ddy * ddy) > 0.2f;

    if (!kept) {
        // dropped channel: out row is exactly 0 — no sig read, no MC loop
        const v4f z = {0.0f, 0.0f, 0.0f, 0.0f};
        #pragma unroll
        for (int u = 0; u < 4; ++u) {
            const int i = t + u * 256;
            if (i < n4) __builtin_nontemporal_store(z, out4 + i);
        }
        for (int i = t + 1024; i < n4; i += 256)
            __builtin_nontemporal_store(z, out4 + i);
        for (int i = (n4 << 2) + t; i < T; i += 256)
            out[base + i] = 0.0f;
        return;
    }

    // ---- stage the streaming loads before the MC scale chain -------------
    v4f v[4];
    #pragma unroll
    for (int u = 0; u < 4; ++u) {
        const int i = t + u * 256;
        if (i < n4) v[u] = __builtin_nontemporal_load(in4 + i);
    }

    // ---- per-wave redundant MC count (no barrier, no LDS) ----------------
    float cnt = 0.0f;
    for (int i = lane; i < NMC; i += 64) { // lanes 0-35: 2 iters, rest: 1
        const float dx = px - mc[2 * i + 0];
        const float dy = py - mc[2 * i + 1];
        cnt += (sqrtf(dx * dx + dy * dy) > 0.2f) ? 1.0f : 0.0f;
    }
    #pragma unroll
    for (int off = 32; off > 0; off >>= 1)  // butterfly: all lanes get sum
        cnt += __shfl_xor(cnt, off, 64);

    const float scale = 1.0f / (1e-8f + cnt / (float)NMC);  // kept == 1

    // ---- scale + store ----------------------------------------------------
    #pragma unroll
    for (int u = 0; u < 4; ++u) {
        const int i = t + u * 256;
        if (i < n4) {
            v4f r = v[u];
            r *= scale;
            __builtin_nontemporal_store(r, out4 + i);
        }
    }
    // generic remainder for n4 > 1024 (not hit at T=3000, kept for safety)
    for (int i = t + 1024; i < n4; i += 256) {
        v4f r = __builtin_nontemporal_load(in4 + i);
        r *= scale;
        __builtin_nontemporal_store(r, out4 + i);
    }
    // scalar tail for T % 4 != 0 (not hit for T=3000)
    for (int i = (n4 << 2) + t; i < T; i += 256) {
        out[base + i] = sig[base + i] * scale;
    }
}

extern "C" void kernel_launch(void* const* d_in, const int* in_sizes, int n_in,
                              void* d_out, int out_size, void* d_ws, size_t ws_size,
                              hipStream_t stream) {
    const float* sig    = (const float*)d_in[0];  // (B, C, T) f32
    const float* pos    = (const float*)d_in[1];  // (B, C, 2) f32
    const float* center = (const float*)d_in[2];  // (2,)      f32
    const float* mc     = (const float*)d_in[3];  // (N, 2)    f32
    float* out          = (float*)d_out;          // (B, C, T) f32

    const int rows = in_sizes[1] / 2;             // B*C = 17472
    const int T    = in_sizes[0] / rows;          // 3000
    const int NMC  = in_sizes[3] / 2;             // 100

    channel_dropout_kernel<<<rows, 256, 0, stream>>>(
        sig, pos, center, mc, out, T, NMC);
}